// Round 4
// baseline (357.824 us; speedup 1.0000x reference)
//
#include <hip/hip_runtime.h>
#include <hip/hip_bf16.h>

// similarity_model: wordvec = emb[wordid]; sim = wordvec . emb[v] for all v;
// out = top-(topk+1) values then indices (indices written as float).
// V=200000, D=300. Memory-bound: must stream 240 MB of embedding once.
// R4: phase1 processes 8 rows/wave-iter with all 10 float4-loads issued
// unconditionally up front (tail chunk de-branched via clamp + zeroed w4),
// doubling in-flight bytes and halving latency exposures per row.

#define V_ROWS 200000
#define D_DIM 300
#define BLOCKS_A 1024
#define THREADS 256
#define WAVES_PER_BLOCK (THREADS / 64)
#define TOTAL_WAVES (BLOCKS_A * WAVES_PER_BLOCK)
#define ROW_STRIDE (TOTAL_WAVES * 8)
#define MAXK 16
#define NCAND (BLOCKS_A * MAXK)
#define THREADS2 512
#define WAVES2 (THREADS2 / 64)

typedef unsigned long long ull;

// ---- packed (value, index) ordering key -----------------------------------
// Monotone transform of float bits in high 32, ~idx in low 32: larger packed
// == (larger value, or equal value with smaller index) — jax tie-breaking.
// All finite floats pack > 0, so 0 is a safe "empty" sentinel.
__device__ __forceinline__ ull pack_vi(float v, int idx) {
    unsigned int u = __float_as_uint(v);
    u ^= (((unsigned int)((int)u >> 31)) | 0x80000000u);
    return ((ull)u << 32) | (unsigned int)(~(unsigned int)idx);
}
__device__ __forceinline__ float unpack_val(ull p) {
    unsigned int u = (unsigned int)(p >> 32);
    u = (u & 0x80000000u) ? (u ^ 0x80000000u) : ~u;
    return __uint_as_float(u);
}
__device__ __forceinline__ int unpack_idx(ull p) {
    return (int)(~(unsigned int)p);
}

__device__ __forceinline__ ull shflx64(ull v, int off) {
    int lo = __shfl_xor((int)(unsigned int)v, off, 64);
    int hi = __shfl_xor((int)(unsigned int)(v >> 32), off, 64);
    return ((ull)(unsigned int)hi << 32) | (unsigned int)lo;
}
__device__ __forceinline__ ull wave_max64(ull v) {
#pragma unroll
    for (int off = 32; off > 0; off >>= 1) {
        ull o = shflx64(v, off);
        v = (o > v) ? o : v;
    }
    return v;  // uniform across all 64 lanes
}

// Insert key into descending-sorted h[16] (branchless shift, static indices).
__device__ __forceinline__ void insert16(ull (&h)[MAXK], ull key) {
    if (key <= h[MAXK - 1]) return;
    ull prev = ~0ull;  // +inf sentinel
#pragma unroll
    for (int j = 0; j < MAXK; ++j) {
        ull cur = h[j];
        ull mn = (prev < key) ? prev : key;
        h[j] = (mn > cur) ? mn : cur;
        prev = cur;
    }
}

__device__ __forceinline__ float dot4(float4 a, float4 b) {
    return a.x * b.x + a.y * b.y + a.z * b.z + a.w * b.w;
}

// ---- phase 1: dot products + per-block top-16 -----------------------------
// Wave = 4 groups of 16 lanes; each group owns TWO rows per iteration.
__global__ __launch_bounds__(THREADS) void sim_phase1(const int* __restrict__ wordid,
                                                      const float* __restrict__ emb,
                                                      ull* __restrict__ cands) {
    const int lane = threadIdx.x & 63;
    const int wv = threadIdx.x >> 6;
    const int sub = lane & 15;   // position within 16-lane group
    const int grp = lane >> 4;   // group 0..3 (row offset within wave iter)
    const int gwave = blockIdx.x * WAVES_PER_BLOCK + wv;

    // tail chunk index, clamped so the load is unconditional (chunks 0..74)
    const int c4 = (sub < 11) ? sub + 64 : 74;

    // word vector: lane's 5 float4 chunks (w4 zeroed for sub>=11 so the
    // clamped tail load contributes 0 — emb is finite normal data)
    const int wid = wordid[0];
    const float4* wrow = (const float4*)(emb + (size_t)wid * D_DIM);
    float4 w0 = wrow[sub];
    float4 w1 = wrow[sub + 16];
    float4 w2 = wrow[sub + 32];
    float4 w3 = wrow[sub + 48];
    float4 w4 = wrow[c4];
    if (sub >= 11) w4 = make_float4(0.f, 0.f, 0.f, 0.f);

    ull h[MAXK];
#pragma unroll
    for (int j = 0; j < MAXK; ++j) h[j] = 0ull;

    for (int base = gwave * 8; base < V_ROWS; base += ROW_STRIDE) {
        int row0 = base + grp;
        int row1 = base + 4 + grp;
        bool v0 = row0 < V_ROWS;
        bool v1 = row1 < V_ROWS;
        const float4* r0 = (const float4*)(emb + (size_t)(v0 ? row0 : 0) * D_DIM);
        const float4* r1 = (const float4*)(emb + (size_t)(v1 ? row1 : 0) * D_DIM);
        // all 10 loads issued up front, no branches
        float4 a0 = r0[sub], a1 = r0[sub + 16], a2 = r0[sub + 32], a3 = r0[sub + 48], a4 = r0[c4];
        float4 b0 = r1[sub], b1 = r1[sub + 16], b2 = r1[sub + 32], b3 = r1[sub + 48], b4 = r1[c4];
        float s0 = dot4(a0, w0) + dot4(a1, w1) + dot4(a2, w2) + dot4(a3, w3) + dot4(a4, w4);
        float s1 = dot4(b0, w0) + dot4(b1, w1) + dot4(b2, w2) + dot4(b3, w3) + dot4(b4, w4);
        // two independent 16-lane reduction chains, interleaved
#pragma unroll
        for (int off = 8; off > 0; off >>= 1) {
            s0 += __shfl_xor(s0, off, 64);
            s1 += __shfl_xor(s1, off, 64);
        }
        insert16(h, v0 ? pack_vi(s0, row0) : 0ull);
        insert16(h, v1 ? pack_vi(s1, row1) : 0ull);
    }

    // block merge: 16 group-lists (4 waves x 4 groups) -> LDS -> wave0
    __shared__ ull lds[16 * MAXK];
    if (sub == 0) {
        int g = (wv << 2) | grp;
#pragma unroll
        for (int j = 0; j < MAXK; ++j) lds[g * MAXK + j] = h[j];
    }
    __syncthreads();
    if (wv == 0) {
        // 256 entries; lane holds 4, kept descending-sorted
        ull m0 = lds[lane], m1 = lds[lane + 64], m2 = lds[lane + 128], m3 = lds[lane + 192];
        ull t;
#define CSWP(a, b) { if (b > a) { t = a; a = b; b = t; } }
        CSWP(m0, m1); CSWP(m2, m3); CSWP(m0, m2); CSWP(m1, m3); CSWP(m1, m2);
#undef CSWP
#pragma unroll
        for (int r = 0; r < MAXK; ++r) {
            ull win = wave_max64(m0);
            if (m0 == win) { m0 = m1; m1 = m2; m2 = m3; m3 = 0ull; }
            if (lane == 0) cands[(size_t)blockIdx.x * MAXK + r] = win;
        }
    }
}

// ---- phase 2: merge candidates -> final top-K -----------------------------
// 512 threads; 32 cands/thread in 4 batches of 8 independent coalesced loads.
__global__ __launch_bounds__(THREADS2) void sim_phase2(const ull* __restrict__ cands,
                                                       const int* __restrict__ topk,
                                                       float* __restrict__ out) {
    const int t = threadIdx.x;
    const int lane = t & 63;
    const int wv = t >> 6;
    int K = topk[0] + 1;
    if (K > MAXK) K = MAXK;

    ull h[MAXK];
#pragma unroll
    for (int j = 0; j < MAXK; ++j) h[j] = 0ull;

    // NCAND = 16384 = 512 threads * 32; batch loads for MLP
#pragma unroll
    for (int b = 0; b < 4; ++b) {
        ull v[8];
#pragma unroll
        for (int j = 0; j < 8; ++j) v[j] = cands[(b * 8 + j) * THREADS2 + t];
#pragma unroll
        for (int j = 0; j < 8; ++j) insert16(h, v[j]);
    }

    __shared__ ull lds[WAVES2 * MAXK];
    // per-wave merge via head extraction; lane 0 records winners to LDS
#pragma unroll
    for (int r = 0; r < MAXK; ++r) {
        ull head = h[0];
        ull win = wave_max64(head);
        if (head == win) {  // consume: shift left (static indices only)
#pragma unroll
            for (int j = 0; j < MAXK - 1; ++j) h[j] = h[j + 1];
            h[MAXK - 1] = 0ull;
        }
        if (lane == 0) lds[wv * MAXK + r] = win;
    }
    __syncthreads();
    if (wv == 0) {
        // 8 waves * 16 = 128 entries; lane holds 2, sorted
        ull m0 = lds[lane], m1 = lds[lane + 64];
        if (m1 > m0) { ull tt = m0; m0 = m1; m1 = tt; }
#pragma unroll
        for (int r = 0; r < MAXK; ++r) {
            ull win = wave_max64(m0);
            if (m0 == win) { m0 = m1; m1 = 0ull; }
            if (lane == 0 && r < K) {
                out[r] = unpack_val(win);
                out[K + r] = (float)unpack_idx(win);
            }
        }
    }
}

extern "C" void kernel_launch(void* const* d_in, const int* in_sizes, int n_in,
                              void* d_out, int out_size, void* d_ws, size_t ws_size,
                              hipStream_t stream) {
    const int* wordid = (const int*)d_in[0];
    const float* emb = (const float*)d_in[1];
    const int* topk = (const int*)d_in[2];
    float* out = (float*)d_out;
    ull* cands = (ull*)d_ws;  // NCAND * 8 = 128 KB

    sim_phase1<<<BLOCKS_A, THREADS, 0, stream>>>(wordid, emb, cands);
    sim_phase2<<<1, THREADS2, 0, stream>>>(cands, topk, out);
}

// Round 5
// 332.971 us; speedup vs baseline: 1.0746x; 1.0746x over previous
//
#include <hip/hip_runtime.h>
#include <hip/hip_bf16.h>

// similarity_model: wordvec = emb[wordid]; sim = wordvec . emb[v] for all v;
// out = top-(topk+1) values then indices (indices written as float).
// V=200000, D=300. Memory-bound: must stream 240 MB of embedding once.
// R5: non-temporal loads for the embedding stream (each byte read exactly
// once; 240 MB >> 32 MB L2, so skip L2 allocation). Structure unchanged from
// R4 (R3=R4 showed phase1 is BW-bound, not latency-bound).

#define V_ROWS 200000
#define D_DIM 300
#define BLOCKS_A 1024
#define THREADS 256
#define WAVES_PER_BLOCK (THREADS / 64)
#define TOTAL_WAVES (BLOCKS_A * WAVES_PER_BLOCK)
#define ROW_STRIDE (TOTAL_WAVES * 8)
#define MAXK 16
#define NCAND (BLOCKS_A * MAXK)
#define THREADS2 512
#define WAVES2 (THREADS2 / 64)

typedef unsigned long long ull;
typedef float vf4 __attribute__((ext_vector_type(4)));

__device__ __forceinline__ vf4 ntload(const vf4* p) {
    return __builtin_nontemporal_load(p);
}

// ---- packed (value, index) ordering key -----------------------------------
// Monotone transform of float bits in high 32, ~idx in low 32: larger packed
// == (larger value, or equal value with smaller index) — jax tie-breaking.
// All finite floats pack > 0, so 0 is a safe "empty" sentinel.
__device__ __forceinline__ ull pack_vi(float v, int idx) {
    unsigned int u = __float_as_uint(v);
    u ^= (((unsigned int)((int)u >> 31)) | 0x80000000u);
    return ((ull)u << 32) | (unsigned int)(~(unsigned int)idx);
}
__device__ __forceinline__ float unpack_val(ull p) {
    unsigned int u = (unsigned int)(p >> 32);
    u = (u & 0x80000000u) ? (u ^ 0x80000000u) : ~u;
    return __uint_as_float(u);
}
__device__ __forceinline__ int unpack_idx(ull p) {
    return (int)(~(unsigned int)p);
}

__device__ __forceinline__ ull shflx64(ull v, int off) {
    int lo = __shfl_xor((int)(unsigned int)v, off, 64);
    int hi = __shfl_xor((int)(unsigned int)(v >> 32), off, 64);
    return ((ull)(unsigned int)hi << 32) | (unsigned int)lo;
}
__device__ __forceinline__ ull wave_max64(ull v) {
#pragma unroll
    for (int off = 32; off > 0; off >>= 1) {
        ull o = shflx64(v, off);
        v = (o > v) ? o : v;
    }
    return v;  // uniform across all 64 lanes
}

// Insert key into descending-sorted h[16] (branchless shift, static indices).
__device__ __forceinline__ void insert16(ull (&h)[MAXK], ull key) {
    if (key <= h[MAXK - 1]) return;
    ull prev = ~0ull;  // +inf sentinel
#pragma unroll
    for (int j = 0; j < MAXK; ++j) {
        ull cur = h[j];
        ull mn = (prev < key) ? prev : key;
        h[j] = (mn > cur) ? mn : cur;
        prev = cur;
    }
}

__device__ __forceinline__ float dot4v(vf4 a, vf4 b) {
    return a.x * b.x + a.y * b.y + a.z * b.z + a.w * b.w;
}

// ---- phase 1: dot products + per-block top-16 -----------------------------
// Wave = 4 groups of 16 lanes; each group owns TWO rows per iteration.
__global__ __launch_bounds__(THREADS) void sim_phase1(const int* __restrict__ wordid,
                                                      const float* __restrict__ emb,
                                                      ull* __restrict__ cands) {
    const int lane = threadIdx.x & 63;
    const int wv = threadIdx.x >> 6;
    const int sub = lane & 15;   // position within 16-lane group
    const int grp = lane >> 4;   // group 0..3 (row offset within wave iter)
    const int gwave = blockIdx.x * WAVES_PER_BLOCK + wv;

    // tail chunk index, clamped so the load is unconditional (chunks 0..74)
    const int c4 = (sub < 11) ? sub + 64 : 74;

    // word vector: lane's 5 float4 chunks (w4 zeroed for sub>=11 so the
    // clamped tail load contributes 0 — emb is finite normal data).
    // These are reused by every block -> keep cacheable (no nt).
    const int wid = wordid[0];
    const vf4* wrow = (const vf4*)(emb + (size_t)wid * D_DIM);
    vf4 w0 = wrow[sub];
    vf4 w1 = wrow[sub + 16];
    vf4 w2 = wrow[sub + 32];
    vf4 w3 = wrow[sub + 48];
    vf4 w4 = wrow[c4];
    if (sub >= 11) w4 = (vf4){0.f, 0.f, 0.f, 0.f};

    ull h[MAXK];
#pragma unroll
    for (int j = 0; j < MAXK; ++j) h[j] = 0ull;

    for (int base = gwave * 8; base < V_ROWS; base += ROW_STRIDE) {
        int row0 = base + grp;
        int row1 = base + 4 + grp;
        bool v0 = row0 < V_ROWS;
        bool v1 = row1 < V_ROWS;
        const vf4* r0 = (const vf4*)(emb + (size_t)(v0 ? row0 : 0) * D_DIM);
        const vf4* r1 = (const vf4*)(emb + (size_t)(v1 ? row1 : 0) * D_DIM);
        // all 10 loads issued up front, no branches, non-temporal (stream)
        vf4 a0 = ntload(r0 + sub), a1 = ntload(r0 + sub + 16), a2 = ntload(r0 + sub + 32),
            a3 = ntload(r0 + sub + 48), a4 = ntload(r0 + c4);
        vf4 b0 = ntload(r1 + sub), b1 = ntload(r1 + sub + 16), b2 = ntload(r1 + sub + 32),
            b3 = ntload(r1 + sub + 48), b4 = ntload(r1 + c4);
        float s0 = dot4v(a0, w0) + dot4v(a1, w1) + dot4v(a2, w2) + dot4v(a3, w3) + dot4v(a4, w4);
        float s1 = dot4v(b0, w0) + dot4v(b1, w1) + dot4v(b2, w2) + dot4v(b3, w3) + dot4v(b4, w4);
        // two independent 16-lane reduction chains, interleaved
#pragma unroll
        for (int off = 8; off > 0; off >>= 1) {
            s0 += __shfl_xor(s0, off, 64);
            s1 += __shfl_xor(s1, off, 64);
        }
        insert16(h, v0 ? pack_vi(s0, row0) : 0ull);
        insert16(h, v1 ? pack_vi(s1, row1) : 0ull);
    }

    // block merge: 16 group-lists (4 waves x 4 groups) -> LDS -> wave0
    __shared__ ull lds[16 * MAXK];
    if (sub == 0) {
        int g = (wv << 2) | grp;
#pragma unroll
        for (int j = 0; j < MAXK; ++j) lds[g * MAXK + j] = h[j];
    }
    __syncthreads();
    if (wv == 0) {
        // 256 entries; lane holds 4, kept descending-sorted
        ull m0 = lds[lane], m1 = lds[lane + 64], m2 = lds[lane + 128], m3 = lds[lane + 192];
        ull t;
#define CSWP(a, b) { if (b > a) { t = a; a = b; b = t; } }
        CSWP(m0, m1); CSWP(m2, m3); CSWP(m0, m2); CSWP(m1, m3); CSWP(m1, m2);
#undef CSWP
#pragma unroll
        for (int r = 0; r < MAXK; ++r) {
            ull win = wave_max64(m0);
            if (m0 == win) { m0 = m1; m1 = m2; m2 = m3; m3 = 0ull; }
            if (lane == 0) cands[(size_t)blockIdx.x * MAXK + r] = win;
        }
    }
}

// ---- phase 2: merge candidates -> final top-K -----------------------------
// 512 threads; 32 cands/thread in 4 batches of 8 independent coalesced loads.
__global__ __launch_bounds__(THREADS2) void sim_phase2(const ull* __restrict__ cands,
                                                       const int* __restrict__ topk,
                                                       float* __restrict__ out) {
    const int t = threadIdx.x;
    const int lane = t & 63;
    const int wv = t >> 6;
    int K = topk[0] + 1;
    if (K > MAXK) K = MAXK;

    ull h[MAXK];
#pragma unroll
    for (int j = 0; j < MAXK; ++j) h[j] = 0ull;

    // NCAND = 16384 = 512 threads * 32; batch loads for MLP
#pragma unroll
    for (int b = 0; b < 4; ++b) {
        ull v[8];
#pragma unroll
        for (int j = 0; j < 8; ++j) v[j] = cands[(b * 8 + j) * THREADS2 + t];
#pragma unroll
        for (int j = 0; j < 8; ++j) insert16(h, v[j]);
    }

    __shared__ ull lds[WAVES2 * MAXK];
    // per-wave merge via head extraction; lane 0 records winners to LDS
#pragma unroll
    for (int r = 0; r < MAXK; ++r) {
        ull head = h[0];
        ull win = wave_max64(head);
        if (head == win) {  // consume: shift left (static indices only)
#pragma unroll
            for (int j = 0; j < MAXK - 1; ++j) h[j] = h[j + 1];
            h[MAXK - 1] = 0ull;
        }
        if (lane == 0) lds[wv * MAXK + r] = win;
    }
    __syncthreads();
    if (wv == 0) {
        // 8 waves * 16 = 128 entries; lane holds 2, sorted
        ull m0 = lds[lane], m1 = lds[lane + 64];
        if (m1 > m0) { ull tt = m0; m0 = m1; m1 = tt; }
#pragma unroll
        for (int r = 0; r < MAXK; ++r) {
            ull win = wave_max64(m0);
            if (m0 == win) { m0 = m1; m1 = 0ull; }
            if (lane == 0 && r < K) {
                out[r] = unpack_val(win);
                out[K + r] = (float)unpack_idx(win);
            }
        }
    }
}

extern "C" void kernel_launch(void* const* d_in, const int* in_sizes, int n_in,
                              void* d_out, int out_size, void* d_ws, size_t ws_size,
                              hipStream_t stream) {
    const int* wordid = (const int*)d_in[0];
    const float* emb = (const float*)d_in[1];
    const int* topk = (const int*)d_in[2];
    float* out = (float*)d_out;
    ull* cands = (ull*)d_ws;  // NCAND * 8 = 128 KB

    sim_phase1<<<BLOCKS_A, THREADS, 0, stream>>>(wordid, emb, cands);
    sim_phase2<<<1, THREADS2, 0, stream>>>(cands, topk, out);
}